// Round 5
// baseline (235.270 us; speedup 1.0000x reference)
//
#include <hip/hip_runtime.h>
#include <math.h>

#define N_NODES 4096
#define F_IN    512
#define E0_EDGES 12288
#define E_TOT   16384   // E0 + N self loops
#define C_CLS   16
#define HID1    32
#define HID2    16
#define T       256
#define MAXDEG  64      // padded deg-list slots per node (actual max in-degree ~15)
#define DB      512     // dense1 blocks
#define RWB     (E_TOT / 4)  // row-sum blocks: 4 waves/block, 1 row/wave

// ---------------------------------------------------------------------------
// zero cnt/deg — must fully precede big_kernel's fill atomics (stream order).
__global__ __launch_bounds__(256) void zero_kernel(int* __restrict__ cnt,
                                                   float* __restrict__ deg) {
    const int i = blockIdx.x * T + threadIdx.x;
    if (i < N_NODES) { cnt[i] = 0; deg[i] = 0.f; }
}

// ---------------------------------------------------------------------------
// big_kernel:
//   blocks [0,DB): dense1 (x@W1+b1 -> bufA), hides under the W_edge stream.
//   blocks [DB,DB+RWB): 4 waves/block, each wave sums one W_edge row (64 KB,
//     float4, fully coalesced, no LDS/no syncthreads), then lane 0 computes
//     ew_raw[e] and immediately does the deg-list fill for edge e:
//     slot bump in cnt[col], srow/ewp store, deg[col] atomic accumulate.
__global__ __launch_bounds__(256) void big_kernel(const float* __restrict__ W_edge,
                                                  const float* __restrict__ b_edge,
                                                  const float* __restrict__ x,
                                                  const float* __restrict__ W1,
                                                  const float* __restrict__ b1,
                                                  const int* __restrict__ ei,
                                                  float* __restrict__ ew_raw,
                                                  float* __restrict__ bufA,
                                                  int* __restrict__ cnt,
                                                  float* __restrict__ deg,
                                                  int* __restrict__ srow,
                                                  float* __restrict__ ewp) {
    const int b = blockIdx.x, t = threadIdx.x;
    if (b < DB) {
        const int idx = b * T + t;
        const int n = idx >> 5, f = idx & 31;
        const float* xr = x + (size_t)n * F_IN;
        float acc = b1[f];
        #pragma unroll 8
        for (int k = 0; k < F_IN; ++k) acc = fmaf(xr[k], W1[k * HID1 + f], acc);
        bufA[idx] = acc;
    } else {
        const int wave = t >> 6, lane = t & 63;
        const int e = (b - DB) * 4 + wave;            // edge == W_edge row index
        const float4* p = (const float4*)(W_edge + (size_t)e * E_TOT);
        float s = 0.f;
        #pragma unroll 4
        for (int i = lane; i < E_TOT / 4; i += 64) {
            float4 v = p[i];
            s += (v.x + v.y) + (v.z + v.w);
        }
        #pragma unroll
        for (int off = 32; off > 0; off >>= 1) s += __shfl_down(s, off, 64);
        if (lane == 0) {
            const float w = s + b_edge[e];
            ew_raw[e] = w;
            const int col = (e < E0_EDGES) ? ei[E0_EDGES + e] : (e - E0_EDGES);
            const int slot = atomicAdd(&cnt[col], 1);
            if (slot < MAXDEG) {
                srow[col * MAXDEG + slot] = (e < E0_EDGES) ? ei[e] : (e - E0_EDGES);
                ewp[col * MAXDEG + slot]  = w;
            }
            atomicAdd(&deg[col], w);
        }
    }
}

// ---------------------------------------------------------------------------
__device__ inline void lsm_store(float acc, float* __restrict__ dst, int n, int f) {
    float mx = acc;
    #pragma unroll
    for (int off = 8; off > 0; off >>= 1) mx = fmaxf(mx, __shfl_xor(mx, off, 16));
    float ss = expf(acc - mx);
    #pragma unroll
    for (int off = 8; off > 0; off >>= 1) ss += __shfl_xor(ss, off, 16);
    dst[n * 16 + f] = acc - mx - logf(ss);
}

// ---------------------------------------------------------------------------
// phase4: blocks [0,512): L2 = agg(bufA,32) w/ on-the-fly deg-scale (writes ew_s),
//                         relu, dense W2(32->16) -> bufB.
//         blocks [512,768): LPA1 = agg(onehot) w/ on-the-fly deg-scale -> yhA.
__global__ __launch_bounds__(256) void phase4_kernel(const float* __restrict__ bufA,
                                                     const int* __restrict__ srow,
                                                     const float* __restrict__ ewp,
                                                     const float* __restrict__ deg,
                                                     const int* __restrict__ cnt,
                                                     const float* __restrict__ W2,
                                                     const float* __restrict__ b2,
                                                     const int* __restrict__ y,
                                                     const int* __restrict__ mask,
                                                     float* __restrict__ bufB,
                                                     float* __restrict__ ew_s,
                                                     float* __restrict__ yhA) {
    const int b = blockIdx.x, t = threadIdx.x;
    if (b < 512) {
        const int nl = t >> 5, f = t & 31;
        const int n = b * 8 + nl;
        const int base = n * MAXDEG;
        const int c = min(cnt[n], MAXDEG);
        float acc = 0.f;
        for (int j = 0; j < c; ++j) {
            const int r = srow[base + j];
            float d = deg[r]; if (isinf(d)) d = 0.f;
            const float w = d * ewp[base + j];
            if (f == 0) ew_s[base + j] = w;
            acc = fmaf(w, bufA[r * HID1 + f], acc);
        }
        acc = fmaxf(acc, 0.f);
        __shared__ float sm[8][HID1];
        sm[nl][f] = acc;
        __syncthreads();
        if (f < 16) {
            float o = b2[f];
            #pragma unroll
            for (int k = 0; k < HID1; ++k) o = fmaf(sm[nl][k], W2[k * 16 + f], o);
            bufB[n * 16 + f] = o;
        }
    } else {
        const int nl = t >> 4, f = t & 15;
        const int n = (b - 512) * 16 + nl;
        const int base = n * MAXDEG;
        const int c = min(cnt[n], MAXDEG);
        float acc = 0.f;
        for (int j = 0; j < c; ++j) {
            const int r = srow[base + j];
            float d = deg[r]; if (isinf(d)) d = 0.f;
            const float w = d * ewp[base + j];
            const float v = (mask[r] != 0 && y[r] == f) ? 1.f : 0.f;
            acc = fmaf(w, v, acc);
        }
        yhA[n * 16 + f] = acc;
    }
}

// ---------------------------------------------------------------------------
// generic paired phase: GCN half (blocks<256, if HASG) + LPA half.
template <bool HASG, bool DENSE, bool GSOFT, bool LSOFT>
__global__ __launch_bounds__(256) void phase_kernel(const float* __restrict__ srcG,
                                                    const float* __restrict__ W,
                                                    const float* __restrict__ bb,
                                                    float* __restrict__ dstG,
                                                    const float* __restrict__ srcL,
                                                    float* __restrict__ dstL,
                                                    const int* __restrict__ srow,
                                                    const float* __restrict__ ew_s,
                                                    const int* __restrict__ cnt) {
    const int b = blockIdx.x, t = threadIdx.x;
    const int nl = t >> 4, f = t & 15;
    if (HASG && b < 256) {
        const int n = b * 16 + nl;
        const int base = n * MAXDEG;
        const int c = min(cnt[n], MAXDEG);
        float acc = 0.f;
        for (int j = 0; j < c; ++j)
            acc = fmaf(ew_s[base + j], srcG[srow[base + j] * 16 + f], acc);
        if constexpr (DENSE) {
            acc = fmaxf(acc, 0.f);
            __shared__ float sm[16][16];
            sm[nl][f] = acc;
            __syncthreads();
            float o = bb[f];
            #pragma unroll
            for (int k = 0; k < 16; ++k) o = fmaf(sm[nl][k], W[k * 16 + f], o);
            dstG[n * 16 + f] = o;
        } else if constexpr (GSOFT) {
            lsm_store(acc, dstG, n, f);
        }
    } else {
        const int n = (b - (HASG ? 256 : 0)) * 16 + nl;
        const int base = n * MAXDEG;
        const int c = min(cnt[n], MAXDEG);
        float acc = 0.f;
        for (int j = 0; j < c; ++j)
            acc = fmaf(ew_s[base + j], srcL[srow[base + j] * 16 + f], acc);
        if constexpr (LSOFT) lsm_store(acc, dstL, n, f);
        else                 dstL[n * 16 + f] = acc;
    }
}

// ---------------------------------------------------------------------------
extern "C" void kernel_launch(void* const* d_in, const int* in_sizes, int n_in,
                              void* d_out, int out_size, void* d_ws, size_t ws_size,
                              hipStream_t stream) {
    const float* x      = (const float*)d_in[0];
    const int*   ei     = (const int*)d_in[1];   // [2*E0] flat: rows then cols
    const int*   y      = (const int*)d_in[2];
    const int*   mask   = (const int*)d_in[3];
    const float* W_edge = (const float*)d_in[4];
    const float* b_edge = (const float*)d_in[5];
    const float* W1 = (const float*)d_in[6];  const float* b1 = (const float*)d_in[7];
    const float* W2 = (const float*)d_in[8];  const float* b2 = (const float*)d_in[9];
    const float* W3 = (const float*)d_in[10]; const float* b3 = (const float*)d_in[11];
    const float* W4 = (const float*)d_in[12]; const float* b4 = (const float*)d_in[13];
    float* out = (float*)d_out;

    // workspace layout (floats unless noted)
    float* ws     = (float*)d_ws;
    float* ew_raw = ws;                          // E_TOT
    float* bufA   = ew_raw + E_TOT;              // N*32
    float* bufB   = bufA + N_NODES * HID1;       // N*16
    float* yhA    = bufB + N_NODES * C_CLS;      // N*16
    float* yhB    = yhA + N_NODES * C_CLS;       // N*16
    float* ewp    = yhB + N_NODES * C_CLS;       // N*MAXDEG
    float* ew_s   = ewp + N_NODES * MAXDEG;      // N*MAXDEG
    float* deg    = ew_s + N_NODES * MAXDEG;     // N
    int*   cnt    = (int*)(deg + N_NODES);       // N
    int*   srow   = cnt + N_NODES;               // N*MAXDEG

    zero_kernel<<<(N_NODES + T - 1) / T, T, 0, stream>>>(cnt, deg);

    big_kernel<<<DB + RWB, T, 0, stream>>>(W_edge, b_edge, x, W1, b1, ei,
                                           ew_raw, bufA, cnt, deg, srow, ewp);

    // phase4: L2 (+ew_s writeback) || LPA1
    phase4_kernel<<<768, T, 0, stream>>>(bufA, srow, ewp, deg, cnt, W2, b2,
                                         y, mask, bufB, ew_s, yhA);
    // phase5: L3 || LPA2
    phase_kernel<true, true, false, false><<<512, T, 0, stream>>>(
        bufB, W3, b3, bufA, yhA, yhB, srow, ew_s, cnt);
    // phase6: L4 || LPA3
    phase_kernel<true, true, false, false><<<512, T, 0, stream>>>(
        bufA, W4, b4, bufB, yhB, yhA, srow, ew_s, cnt);
    // phase7: GCN agg + log_softmax -> out[0:] || LPA4
    phase_kernel<true, false, true, false><<<512, T, 0, stream>>>(
        bufB, nullptr, nullptr, out, yhA, yhB, srow, ew_s, cnt);
    // phase8: LPA5 + log_softmax -> out[N*C:]
    phase_kernel<false, false, false, true><<<256, T, 0, stream>>>(
        nullptr, nullptr, nullptr, nullptr, yhB, out + (size_t)N_NODES * C_CLS,
        srow, ew_s, cnt);
}

// Round 7
// 194.645 us; speedup vs baseline: 1.2087x; 1.2087x over previous
//
#include <hip/hip_runtime.h>
#include <math.h>

#define N_NODES 4096
#define F_IN    512
#define E0_EDGES 12288
#define E_TOT   16384   // E0 + N self loops
#define C_CLS   16
#define HID1    32
#define HID2    16
#define T       256
#define MAXDEG  64      // padded deg-list slots per node (actual max in-degree ~15)
#define DB      512     // dense1 blocks
#define ZB      4       // zero blocks (cnt + deg)
#define RB0     (DB + ZB)

typedef float vfloat4 __attribute__((ext_vector_type(4)));  // native vec for nontemporal builtin

// ---------------------------------------------------------------------------
// big_kernel: blocks [0,DB): dense1 (x@W1+b1 -> bufA);
//             blocks [DB,RB0): zero cnt/deg;
//             blocks [RB0, RB0+E_TOT): block-per-row W_edge row sum.
// Block-per-row (NOT wave-per-row): one contiguous 64 KB stream per block is
// the fastest DRAM shape measured (R4 215.6 vs R5 235.3 with wave-per-row).
__global__ __launch_bounds__(256) void big_kernel(const float* __restrict__ W_edge,
                                                  const float* __restrict__ b_edge,
                                                  const float* __restrict__ x,
                                                  const float* __restrict__ W1,
                                                  const float* __restrict__ b1,
                                                  float* __restrict__ ew_raw,
                                                  float* __restrict__ bufA,
                                                  int* __restrict__ cnt,
                                                  float* __restrict__ deg) {
    const int b = blockIdx.x, t = threadIdx.x;
    if (b < DB) {
        const int idx = b * T + t;
        const int n = idx >> 5, f = idx & 31;
        const float* xr = x + (size_t)n * F_IN;
        float acc = b1[f];
        #pragma unroll 8
        for (int k = 0; k < F_IN; ++k) acc = fmaf(xr[k], W1[k * HID1 + f], acc);
        bufA[idx] = acc;
    } else if (b < RB0) {
        for (int i = (b - DB) * T + t; i < N_NODES; i += ZB * T) {
            cnt[i] = 0; deg[i] = 0.f;
        }
    } else {
        const int row = b - RB0;
        const vfloat4* p = (const vfloat4*)(W_edge + (size_t)row * E_TOT) + t;
        // 16 independent nontemporal float4 loads in flight (full MLP),
        // then a 4-way partial-sum tree.
        vfloat4 v[16];
        #pragma unroll
        for (int i = 0; i < 16; ++i) v[i] = __builtin_nontemporal_load(p + i * T);
        float s0 = 0.f, s1 = 0.f, s2 = 0.f, s3 = 0.f;
        #pragma unroll
        for (int i = 0; i < 16; i += 4) {
            s0 += (v[i+0].x + v[i+0].y) + (v[i+0].z + v[i+0].w);
            s1 += (v[i+1].x + v[i+1].y) + (v[i+1].z + v[i+1].w);
            s2 += (v[i+2].x + v[i+2].y) + (v[i+2].z + v[i+2].w);
            s3 += (v[i+3].x + v[i+3].y) + (v[i+3].z + v[i+3].w);
        }
        float s = (s0 + s1) + (s2 + s3);
        #pragma unroll
        for (int off = 32; off > 0; off >>= 1) s += __shfl_down(s, off, 64);
        __shared__ float sm[4];
        const int lane = t & 63, wave = t >> 6;
        if (lane == 0) sm[wave] = s;
        __syncthreads();
        if (t == 0) ew_raw[row] = (sm[0] + sm[1]) + (sm[2] + sm[3]) + b_edge[row];
    }
}

// ---------------------------------------------------------------------------
// fill: per edge, bump a slot in col's deg-list, store (srow, raw w), accumulate deg.
__global__ __launch_bounds__(256) void fill_kernel(const int* __restrict__ ei,
                                                   const float* __restrict__ ew_raw,
                                                   int* __restrict__ cnt,
                                                   float* __restrict__ deg,
                                                   int* __restrict__ srow,
                                                   float* __restrict__ ewp) {
    const int e = blockIdx.x * T + threadIdx.x;   // grid = E_TOT/T exactly
    const int rowe = (e < E0_EDGES) ? ei[e] : (e - E0_EDGES);
    const int col  = (e < E0_EDGES) ? ei[E0_EDGES + e] : (e - E0_EDGES);
    const float w = ew_raw[e];
    const int slot = atomicAdd(&cnt[col], 1);
    if (slot < MAXDEG) {
        srow[col * MAXDEG + slot] = rowe;
        ewp[col * MAXDEG + slot]  = w;
    }
    atomicAdd(&deg[col], w);
}

// ---------------------------------------------------------------------------
__device__ inline void lsm_store(float acc, float* __restrict__ dst, int n, int f) {
    float mx = acc;
    #pragma unroll
    for (int off = 8; off > 0; off >>= 1) mx = fmaxf(mx, __shfl_xor(mx, off, 16));
    float ss = expf(acc - mx);
    #pragma unroll
    for (int off = 8; off > 0; off >>= 1) ss += __shfl_xor(ss, off, 16);
    dst[n * 16 + f] = acc - mx - logf(ss);
}

// ---------------------------------------------------------------------------
// phase4: blocks [0,512): L2 = agg(bufA,32) w/ on-the-fly scale (writes ew_s),
//                         relu, dense W2(32->16) -> bufB.
//         blocks [512,768): LPA1 = agg(onehot) w/ on-the-fly scale -> yhA.
__global__ __launch_bounds__(256) void phase4_kernel(const float* __restrict__ bufA,
                                                     const int* __restrict__ srow,
                                                     const float* __restrict__ ewp,
                                                     const float* __restrict__ deg,
                                                     const int* __restrict__ cnt,
                                                     const float* __restrict__ W2,
                                                     const float* __restrict__ b2,
                                                     const int* __restrict__ y,
                                                     const int* __restrict__ mask,
                                                     float* __restrict__ bufB,
                                                     float* __restrict__ ew_s,
                                                     float* __restrict__ yhA) {
    const int b = blockIdx.x, t = threadIdx.x;
    if (b < 512) {
        const int nl = t >> 5, f = t & 31;
        const int n = b * 8 + nl;
        const int base = n * MAXDEG;
        const int c = min(cnt[n], MAXDEG);
        float acc = 0.f;
        for (int j = 0; j < c; ++j) {
            const int r = srow[base + j];
            float d = deg[r]; if (isinf(d)) d = 0.f;
            const float w = d * ewp[base + j];
            if (f == 0) ew_s[base + j] = w;
            acc = fmaf(w, bufA[r * HID1 + f], acc);
        }
        acc = fmaxf(acc, 0.f);
        __shared__ float sm[8][HID1];
        sm[nl][f] = acc;
        __syncthreads();
        if (f < 16) {
            float o = b2[f];
            #pragma unroll
            for (int k = 0; k < HID1; ++k) o = fmaf(sm[nl][k], W2[k * 16 + f], o);
            bufB[n * 16 + f] = o;
        }
    } else {
        const int nl = t >> 4, f = t & 15;
        const int n = (b - 512) * 16 + nl;
        const int base = n * MAXDEG;
        const int c = min(cnt[n], MAXDEG);
        float acc = 0.f;
        for (int j = 0; j < c; ++j) {
            const int r = srow[base + j];
            float d = deg[r]; if (isinf(d)) d = 0.f;
            const float w = d * ewp[base + j];
            const float v = (mask[r] != 0 && y[r] == f) ? 1.f : 0.f;
            acc = fmaf(w, v, acc);
        }
        yhA[n * 16 + f] = acc;
    }
}

// ---------------------------------------------------------------------------
// generic paired phase: GCN half (blocks<256, if HASG) + LPA half.
template <bool HASG, bool DENSE, bool GSOFT, bool LSOFT>
__global__ __launch_bounds__(256) void phase_kernel(const float* __restrict__ srcG,
                                                    const float* __restrict__ W,
                                                    const float* __restrict__ bb,
                                                    float* __restrict__ dstG,
                                                    const float* __restrict__ srcL,
                                                    float* __restrict__ dstL,
                                                    const int* __restrict__ srow,
                                                    const float* __restrict__ ew_s,
                                                    const int* __restrict__ cnt) {
    const int b = blockIdx.x, t = threadIdx.x;
    const int nl = t >> 4, f = t & 15;
    if (HASG && b < 256) {
        const int n = b * 16 + nl;
        const int base = n * MAXDEG;
        const int c = min(cnt[n], MAXDEG);
        float acc = 0.f;
        for (int j = 0; j < c; ++j)
            acc = fmaf(ew_s[base + j], srcG[srow[base + j] * 16 + f], acc);
        if constexpr (DENSE) {
            acc = fmaxf(acc, 0.f);
            __shared__ float sm[16][16];
            sm[nl][f] = acc;
            __syncthreads();
            float o = bb[f];
            #pragma unroll
            for (int k = 0; k < 16; ++k) o = fmaf(sm[nl][k], W[k * 16 + f], o);
            dstG[n * 16 + f] = o;
        } else if constexpr (GSOFT) {
            lsm_store(acc, dstG, n, f);
        }
    } else {
        const int n = (b - (HASG ? 256 : 0)) * 16 + nl;
        const int base = n * MAXDEG;
        const int c = min(cnt[n], MAXDEG);
        float acc = 0.f;
        for (int j = 0; j < c; ++j)
            acc = fmaf(ew_s[base + j], srcL[srow[base + j] * 16 + f], acc);
        if constexpr (LSOFT) lsm_store(acc, dstL, n, f);
        else                 dstL[n * 16 + f] = acc;
    }
}

// ---------------------------------------------------------------------------
extern "C" void kernel_launch(void* const* d_in, const int* in_sizes, int n_in,
                              void* d_out, int out_size, void* d_ws, size_t ws_size,
                              hipStream_t stream) {
    const float* x      = (const float*)d_in[0];
    const int*   ei     = (const int*)d_in[1];   // [2*E0] flat: rows then cols
    const int*   y      = (const int*)d_in[2];
    const int*   mask   = (const int*)d_in[3];
    const float* W_edge = (const float*)d_in[4];
    const float* b_edge = (const float*)d_in[5];
    const float* W1 = (const float*)d_in[6];  const float* b1 = (const float*)d_in[7];
    const float* W2 = (const float*)d_in[8];  const float* b2 = (const float*)d_in[9];
    const float* W3 = (const float*)d_in[10]; const float* b3 = (const float*)d_in[11];
    const float* W4 = (const float*)d_in[12]; const float* b4 = (const float*)d_in[13];
    float* out = (float*)d_out;

    // workspace layout (floats unless noted)
    float* ws     = (float*)d_ws;
    float* ew_raw = ws;                          // E_TOT
    float* bufA   = ew_raw + E_TOT;              // N*32
    float* bufB   = bufA + N_NODES * HID1;       // N*16
    float* yhA    = bufB + N_NODES * C_CLS;      // N*16
    float* yhB    = yhA + N_NODES * C_CLS;       // N*16
    float* ewp    = yhB + N_NODES * C_CLS;       // N*MAXDEG
    float* ew_s   = ewp + N_NODES * MAXDEG;      // N*MAXDEG
    float* deg    = ew_s + N_NODES * MAXDEG;     // N
    int*   cnt    = (int*)(deg + N_NODES);       // N
    int*   srow   = cnt + N_NODES;               // N*MAXDEG

    big_kernel<<<RB0 + E_TOT, T, 0, stream>>>(W_edge, b_edge, x, W1, b1,
                                              ew_raw, bufA, cnt, deg);
    fill_kernel<<<E_TOT / T, T, 0, stream>>>(ei, ew_raw, cnt, deg, srow, ewp);

    // phase4: L2 (+ew_s writeback) || LPA1
    phase4_kernel<<<768, T, 0, stream>>>(bufA, srow, ewp, deg, cnt, W2, b2,
                                         y, mask, bufB, ew_s, yhA);
    // phase5: L3 || LPA2
    phase_kernel<true, true, false, false><<<512, T, 0, stream>>>(
        bufB, W3, b3, bufA, yhA, yhB, srow, ew_s, cnt);
    // phase6: L4 || LPA3
    phase_kernel<true, true, false, false><<<512, T, 0, stream>>>(
        bufA, W4, b4, bufB, yhB, yhA, srow, ew_s, cnt);
    // phase7: GCN agg + log_softmax -> out[0:] || LPA4
    phase_kernel<true, false, true, false><<<512, T, 0, stream>>>(
        bufB, nullptr, nullptr, out, yhA, yhB, srow, ew_s, cnt);
    // phase8: LPA5 + log_softmax -> out[N*C:]
    phase_kernel<false, false, false, true><<<256, T, 0, stream>>>(
        nullptr, nullptr, nullptr, nullptr, yhB, out + (size_t)N_NODES * C_CLS,
        srow, ew_s, cnt);
}